// Round 1
// baseline (1663.236 us; speedup 1.0000x reference)
//
#include <hip/hip_runtime.h>
#include <hip/hip_bf16.h>

#define NV 10000
#define NF 20000
#define DIMV 512

typedef short bf16x8 __attribute__((ext_vector_type(8)));
typedef float f32x4 __attribute__((ext_vector_type(4)));

__device__ __forceinline__ uint pk2(float a, float b) {
    union { __hip_bfloat162 h; uint u; } cv;
    cv.h = __float22bfloat162_rn(make_float2(a, b));
    return cv.u;
}

__device__ __forceinline__ void gll16(const void* g, void* l) {
    __builtin_amdgcn_global_load_lds(
        (const __attribute__((address_space(1))) void*)g,
        (__attribute__((address_space(3))) void*)l,
        16, 0, 0);
}

// ---------------------------------------------------------------------------
// Kernel 1: convert both weight matrices to bf16.
// ---------------------------------------------------------------------------
__global__ __launch_bounds__(256) void prep_kernel(
    const float* __restrict__ Wp, const float* __restrict__ Wd,
    ushort* __restrict__ Wpb, ushort* __restrict__ Wdb)
{
    const int g = blockIdx.x * 256 + threadIdx.x;   // 0..262143
    const int half = 131072;                        // 524288/4
    if (g < half) {
        const int i = g * 4;
        const float4 v = *(const float4*)(Wp + i);
        *(uint2*)(Wpb + i) = make_uint2(pk2(v.x, v.y), pk2(v.z, v.w));
    } else {
        const int i = (g - half) * 4;
        const float4 v = *(const float4*)(Wd + i);
        *(uint2*)(Wdb + i) = make_uint2(pk2(v.x, v.y), pk2(v.z, v.w));
    }
}

// ---------------------------------------------------------------------------
// Kernel 2: f = mean |primal[faces] - dual|, emit fT (512 x 20000 bf16) and
// dual_cat (20000 x 1024 bf16). 64 faces per block, LDS transpose for fT.
// ---------------------------------------------------------------------------
__global__ __launch_bounds__(256) void f_kernel(
    const float* __restrict__ primal, const float* __restrict__ dual,
    const int* __restrict__ faces,
    ushort* __restrict__ fT, ushort* __restrict__ dcat)
{
    __shared__ __align__(16) ushort f_lds[64 * DIMV];   // 64 KB
    const int t = threadIdx.x;
    const int wave = t >> 6, lane = t & 63;
    const int jbase = blockIdx.x * 64;

    for (int r = 0; r < 16; ++r) {
        const int fl = r * 4 + wave;
        const int j = jbase + fl;
        if (j < NF) {
            const int v0 = faces[j * 3 + 0];
            const int v1 = faces[j * 3 + 1];
            const int v2 = faces[j * 3 + 2];
#pragma unroll
            for (int p = 0; p < 2; ++p) {
                const int d = p * 256 + lane * 4;
                const float4 dv = *(const float4*)(dual   + (size_t)j  * DIMV + d);
                const float4 av = *(const float4*)(primal + (size_t)v0 * DIMV + d);
                const float4 bv = *(const float4*)(primal + (size_t)v1 * DIMV + d);
                const float4 cv = *(const float4*)(primal + (size_t)v2 * DIMV + d);
                float4 fv;
                fv.x = (fabsf(av.x - dv.x) + fabsf(bv.x - dv.x) + fabsf(cv.x - dv.x)) * (1.0f / 3.0f);
                fv.y = (fabsf(av.y - dv.y) + fabsf(bv.y - dv.y) + fabsf(cv.y - dv.y)) * (1.0f / 3.0f);
                fv.z = (fabsf(av.z - dv.z) + fabsf(bv.z - dv.z) + fabsf(cv.z - dv.z)) * (1.0f / 3.0f);
                fv.w = (fabsf(av.w - dv.w) + fabsf(bv.w - dv.w) + fabsf(cv.w - dv.w)) * (1.0f / 3.0f);
                const uint2 du = make_uint2(pk2(dv.x, dv.y), pk2(dv.z, dv.w));
                const uint2 fu = make_uint2(pk2(fv.x, fv.y), pk2(fv.z, fv.w));
                *(uint2*)(dcat + (size_t)j * 1024 + d)       = du;
                *(uint2*)(dcat + (size_t)j * 1024 + 512 + d) = fu;
                *(uint2*)(&f_lds[fl * DIMV + d])             = fu;
            }
        }
    }
    __syncthreads();
    const int nj = (NF - jbase < 64) ? (NF - jbase) : 64;
#pragma unroll
    for (int dd = 0; dd < 2; ++dd) {
        const int d = dd * 256 + t;
        ushort* __restrict__ dst = fT + (size_t)d * NF + jbase;
        for (int c = 0; c < nj; c += 4) {
            ushort4 v;
            v.x = f_lds[(c + 0) * DIMV + d];
            v.y = f_lds[(c + 1) * DIMV + d];
            v.z = f_lds[(c + 2) * DIMV + d];
            v.w = f_lds[(c + 3) * DIMV + d];
            *(ushort4*)(dst + c) = v;
        }
    }
}

// ---------------------------------------------------------------------------
// Kernel 3: mapped += A @ f   (A fp32 on-the-fly -> bf16, B = fT, NT GEMM)
// 128x128 tile, BK=32, split-K over blockIdx.z (157/156/156/156 chunks).
// A staged manually into stride-80B LDS rows (bank-group spread), B async.
// ---------------------------------------------------------------------------
__global__ __launch_bounds__(256) void gemm1_kernel(
    const float* __restrict__ A,     // NV x NF fp32
    const ushort* __restrict__ Bt,   // DIMV x NF bf16
    float* __restrict__ C)           // NV x DIMV f32 (atomic accumulate)
{
    __shared__ __align__(16) ushort a_lds[128 * 40];  // 80 B rows
    __shared__ __align__(16) ushort b_lds[128 * 32];  // 64 B rows
    const int t = threadIdx.x;
    const int wave = t >> 6, lane = t & 63;
    const int m0 = blockIdx.y * 128;
    const int n0 = blockIdx.x * 128;
    const int z  = blockIdx.z;
    const int cbeg = (z == 0) ? 0 : 157 + (z - 1) * 156;
    const int cnum = (z == 0) ? 157 : 156;

    // A staging: thread t -> row t/2, 16 consecutive f32 at col (t&1)*16
    const int ra = t >> 1, ha = t & 1;
    const bool aok = (m0 + ra) < NV;
    const float* aptr = A + (size_t)(m0 + ra) * NF + ha * 16;
    ushort* awr = &a_lds[ra * 40 + ha * 16];

    // B staging: 16B chunks c = t and t+256: row = c>>2, q = c&3
    const ushort* bptr0 = Bt + (size_t)(n0 + (t >> 2)) * NF + (t & 3) * 8;
    const ushort* bptr1 = Bt + (size_t)(n0 + (t >> 2) + 64) * NF + (t & 3) * 8;
    ushort* bw0 = &b_lds[t * 8];
    ushort* bw1 = &b_lds[(t + 256) * 8];

    const int wm = (wave >> 1) * 64, wn = (wave & 1) * 64;
    const int fm = lane & 15, kh = lane >> 4;

    const ushort* ard[4];
    const ushort* brd[4];
#pragma unroll
    for (int i = 0; i < 4; ++i) {
        ard[i] = &a_lds[(wm + i * 16 + fm) * 40 + kh * 8];
        brd[i] = &b_lds[(wn + i * 16 + fm) * 32 + kh * 8];
    }

    f32x4 acc[4][4] = {};

    for (int kc = 0; kc < cnum; ++kc) {
        const int k0 = (cbeg + kc) * 32;
        __syncthreads();
        gll16(bptr0 + k0, bw0);
        gll16(bptr1 + k0, bw1);
        if (aok) {
            const float4 x0 = *(const float4*)(aptr + k0 + 0);
            const float4 x1 = *(const float4*)(aptr + k0 + 4);
            const float4 x2 = *(const float4*)(aptr + k0 + 8);
            const float4 x3 = *(const float4*)(aptr + k0 + 12);
            const uint4 w0 = make_uint4(pk2(x0.x, x0.y), pk2(x0.z, x0.w),
                                        pk2(x1.x, x1.y), pk2(x1.z, x1.w));
            const uint4 w1 = make_uint4(pk2(x2.x, x2.y), pk2(x2.z, x2.w),
                                        pk2(x3.x, x3.y), pk2(x3.z, x3.w));
            *(uint4*)(awr)     = w0;
            *(uint4*)(awr + 8) = w1;
        }
        __syncthreads();
        bf16x8 af[4], bfv[4];
#pragma unroll
        for (int i = 0; i < 4; ++i) af[i]  = *(const bf16x8*)ard[i];
#pragma unroll
        for (int i = 0; i < 4; ++i) bfv[i] = *(const bf16x8*)brd[i];
#pragma unroll
        for (int mi = 0; mi < 4; ++mi)
#pragma unroll
            for (int ni = 0; ni < 4; ++ni)
                acc[mi][ni] = __builtin_amdgcn_mfma_f32_16x16x32_bf16(
                    af[mi], bfv[ni], acc[mi][ni], 0, 0, 0);
    }

#pragma unroll
    for (int mi = 0; mi < 4; ++mi) {
        const int rb = m0 + wm + mi * 16 + kh * 4;
#pragma unroll
        for (int ni = 0; ni < 4; ++ni) {
            const int col = n0 + wn + ni * 16 + fm;
#pragma unroll
            for (int r = 0; r < 4; ++r) {
                if (rb + r < NV)
                    atomicAdd(&C[(size_t)(rb + r) * DIMV + col], acc[mi][ni][r]);
            }
        }
    }
}

// ---------------------------------------------------------------------------
// Kernel 4: primal_cat = [bf16(primal), bf16(mapped)]
// ---------------------------------------------------------------------------
__global__ __launch_bounds__(256) void catp_kernel(
    const float* __restrict__ primal, const float* __restrict__ mapped,
    ushort* __restrict__ pcat)
{
    const int g = blockIdx.x * 256 + threadIdx.x;
    if (g >= NV * 128) return;
    const int row = g >> 7;
    const int d = (g & 127) * 4;
    const float4 p = *(const float4*)(primal + (size_t)row * DIMV + d);
    const float4 m = *(const float4*)(mapped + (size_t)row * DIMV + d);
    *(uint2*)(pcat + (size_t)row * 1024 + d)       = make_uint2(pk2(p.x, p.y), pk2(p.z, p.w));
    *(uint2*)(pcat + (size_t)row * 1024 + 512 + d) = make_uint2(pk2(m.x, m.y), pk2(m.z, m.w));
}

// ---------------------------------------------------------------------------
// Kernel 5: generic bf16 NT GEMM + bias + relu, fp32 store.
// C[m][n] = relu(sum_k A[m][k]*B[n][k] + bias[n]).  m97 structure.
// ---------------------------------------------------------------------------
__global__ __launch_bounds__(256) void gemm_bt_kernel(
    const ushort* __restrict__ A, const int lda, const int M,
    const ushort* __restrict__ B, const int ldb,
    const float* __restrict__ bias,
    float* __restrict__ C, const int ldc,
    const int K)
{
    __shared__ __align__(16) ushort a_lds[128 * 32];
    __shared__ __align__(16) ushort b_lds[128 * 32];
    const int t = threadIdx.x;
    const int wave = t >> 6, lane = t & 63;
    const int m0 = blockIdx.y * 128;
    const int n0 = blockIdx.x * 128;

    const int cr = t >> 2, cq = t & 3;
    const ushort* ap0 = A + (size_t)(m0 + cr) * lda + cq * 8;
    const ushort* ap1 = A + (size_t)(m0 + cr + 64) * lda + cq * 8;
    const ushort* bp0 = B + (size_t)(n0 + cr) * ldb + cq * 8;
    const ushort* bp1 = B + (size_t)(n0 + cr + 64) * ldb + cq * 8;
    ushort* aw0 = &a_lds[t * 8];
    ushort* aw1 = &a_lds[(t + 256) * 8];
    ushort* bw0 = &b_lds[t * 8];
    ushort* bw1 = &b_lds[(t + 256) * 8];

    const int wm = (wave >> 1) * 64, wn = (wave & 1) * 64;
    const int fm = lane & 15, kh = lane >> 4;

    const ushort* ard[4];
    const ushort* brd[4];
#pragma unroll
    for (int i = 0; i < 4; ++i) {
        ard[i] = &a_lds[(wm + i * 16 + fm) * 32 + kh * 8];
        brd[i] = &b_lds[(wn + i * 16 + fm) * 32 + kh * 8];
    }

    f32x4 acc[4][4] = {};
    const int kn = K >> 5;
    for (int kc = 0; kc < kn; ++kc) {
        const int k0 = kc * 32;
        __syncthreads();
        gll16(ap0 + k0, aw0);
        gll16(ap1 + k0, aw1);
        gll16(bp0 + k0, bw0);
        gll16(bp1 + k0, bw1);
        __syncthreads();
        bf16x8 af[4], bfv[4];
#pragma unroll
        for (int i = 0; i < 4; ++i) af[i]  = *(const bf16x8*)ard[i];
#pragma unroll
        for (int i = 0; i < 4; ++i) bfv[i] = *(const bf16x8*)brd[i];
#pragma unroll
        for (int mi = 0; mi < 4; ++mi)
#pragma unroll
            for (int ni = 0; ni < 4; ++ni)
                acc[mi][ni] = __builtin_amdgcn_mfma_f32_16x16x32_bf16(
                    af[mi], bfv[ni], acc[mi][ni], 0, 0, 0);
    }

#pragma unroll
    for (int mi = 0; mi < 4; ++mi) {
        const int rb = m0 + wm + mi * 16 + kh * 4;
#pragma unroll
        for (int ni = 0; ni < 4; ++ni) {
            const int col = n0 + wn + ni * 16 + fm;
            const float bv = bias[col];
#pragma unroll
            for (int r = 0; r < 4; ++r) {
                if (rb + r < M) {
                    float v = acc[mi][ni][r] + bv;
                    C[(size_t)(rb + r) * ldc + col] = v > 0.0f ? v : 0.0f;
                }
            }
        }
    }
}

// ---------------------------------------------------------------------------
// ws layout (bytes):
//   fT       @ 0          : 512*20000*2   = 20,480,000
//   dcat     @ 20,480,000 : 20000*1024*2  = 40,960,000
//   Wdb      @ 61,440,000 : 512*1024*2    =  1,048,576
//   Wpb      @ 62,488,576 : 512*1024*2    =  1,048,576
//   pcat     @ 63,537,152 : 10000*1024*2  = 20,480,000
//   mapped   @ 84,017,152 : 10000*512*4   = 20,480,000   (end 104,497,152)
// OOB staging reads of dcat/pcat tails land in the following region (safe).
// ---------------------------------------------------------------------------
extern "C" void kernel_launch(void* const* d_in, const int* in_sizes, int n_in,
                              void* d_out, int out_size, void* d_ws, size_t ws_size,
                              hipStream_t stream)
{
    const float* primal = (const float*)d_in[0];
    const float* dual   = (const float*)d_in[1];
    const float* Amat   = (const float*)d_in[2];
    const int*   faces  = (const int*)d_in[3];
    const float* Wp     = (const float*)d_in[4];
    const float* bp     = (const float*)d_in[5];
    const float* Wd     = (const float*)d_in[6];
    const float* bd     = (const float*)d_in[7];

    float* out_primal = (float*)d_out;
    float* out_dual   = out_primal + (size_t)NV * DIMV;

    char* ws = (char*)d_ws;
    ushort* fT     = (ushort*)(ws);
    ushort* dcat   = (ushort*)(ws + 20480000);
    ushort* Wdb    = (ushort*)(ws + 61440000);
    ushort* Wpb    = (ushort*)(ws + 62488576);
    ushort* pcat   = (ushort*)(ws + 63537152);
    float*  mapped = (float*)(ws + 84017152);

    prep_kernel<<<1024, 256, 0, stream>>>(Wp, Wd, Wpb, Wdb);
    f_kernel<<<313, 256, 0, stream>>>(primal, dual, faces, fT, dcat);
    hipMemsetAsync(mapped, 0, (size_t)NV * DIMV * sizeof(float), stream);
    gemm1_kernel<<<dim3(4, 79, 4), 256, 0, stream>>>(Amat, fT, mapped);
    catp_kernel<<<5000, 256, 0, stream>>>(primal, mapped, pcat);
    gemm_bt_kernel<<<dim3(4, 79), 256, 0, stream>>>(pcat, 1024, NV, Wpb, 1024, bp,
                                                    out_primal, DIMV, 1024);
    gemm_bt_kernel<<<dim3(4, 157), 256, 0, stream>>>(dcat, 1024, NF, Wdb, 1024, bd,
                                                     out_dual, DIMV, 1024);
}